// Round 4
// baseline (194.914 us; speedup 1.0000x reference)
//
#include <hip/hip_runtime.h>
#include <hip/hip_cooperative_groups.h>

namespace cg = cooperative_groups;

#define BB 4
#define TT 1024
#define DD 1024
#define UU 64
#define HW 32   // WIDTH/2

// tanh via hw exp: tanh(|x|) = (1 - e^{-2|x|}) / (1 + e^{-2|x|}), no overflow, ~1e-6 abs err
__device__ __forceinline__ float tanh_fast(float x) {
  float ax = __builtin_fabsf(x);
  float t = __expf(-2.0f * ax);                     // (0, 1]
  float r = (1.0f - t) * __builtin_amdgcn_rcpf(1.0f + t);
  return __builtin_copysignf(r, x);
}

// ---------------------------------------------------------------------------
// proj phase (R2-proven shape): 8 rows/tile, thread = u-pair(32) x sel(2) x
// d-eighth(8 x 128d). x-tile in LDS (wave-uniform broadcast reads), 8-partial
// LDS reduce. smem usage: [0,8192) x-tile, [8192,16384) partials.
// ---------------------------------------------------------------------------
__device__ __forceinline__ void proj_phase(
    float* __restrict__ smem, int tile,
    const float* __restrict__ x, const float* __restrict__ Wt,
    const float* __restrict__ Wx, float* __restrict__ qo, float* __restrict__ ko)
{
  const int tid  = threadIdx.x;
  const int row0 = tile * 8;
  float* xs  = smem;            // 8*1024
  float* red = smem + 8192;     // [kq][1024]

  {
    const float4* src = (const float4*)(x + (size_t)row0 * DD);
    float4* dst = (float4*)xs;
    #pragma unroll
    for (int i = 0; i < 4; ++i) dst[tid + 512 * i] = src[tid + 512 * i];
  }
  __syncthreads();

  const int u2  = tid & 31;          // u pair {2*u2, 2*u2+1}
  const int sel = (tid >> 5) & 1;    // 0 -> Wt/q, 1 -> Wx/k
  const int kq  = tid >> 6;          // d-eighth 0..7 (128 d each)
  const float* __restrict__ Wp = (sel ? Wx : Wt) + 2 * u2;

  float acc0[8], acc1[8];
  #pragma unroll
  for (int r = 0; r < 8; ++r) { acc0[r] = 0.f; acc1[r] = 0.f; }

  const int dbeg = kq * 128;
  #pragma unroll 4
  for (int dc = dbeg; dc < dbeg + 128; dc += 4) {
    float2 w0 = *(const float2*)(Wp + (size_t)(dc + 0) * UU);
    float2 w1 = *(const float2*)(Wp + (size_t)(dc + 1) * UU);
    float2 w2 = *(const float2*)(Wp + (size_t)(dc + 2) * UU);
    float2 w3 = *(const float2*)(Wp + (size_t)(dc + 3) * UU);
    #pragma unroll
    for (int r = 0; r < 8; ++r) {
      float4 xv = *(const float4*)(xs + r * DD + dc);    // wave-uniform broadcast
      acc0[r] = __builtin_fmaf(xv.x, w0.x, __builtin_fmaf(xv.y, w1.x,
                __builtin_fmaf(xv.z, w2.x, __builtin_fmaf(xv.w, w3.x, acc0[r]))));
      acc1[r] = __builtin_fmaf(xv.x, w0.y, __builtin_fmaf(xv.y, w1.y,
                __builtin_fmaf(xv.z, w2.y, __builtin_fmaf(xv.w, w3.y, acc1[r]))));
    }
  }

  #pragma unroll
  for (int r = 0; r < 8; ++r) {
    *(float2*)(red + kq * 1024 + (sel * 8 + r) * 64 + 2 * u2) =
        make_float2(acc0[r], acc1[r]);
  }
  __syncthreads();

  #pragma unroll
  for (int m = 0; m < 2; ++m) {
    int oi = tid + 512 * m;            // (sel:1)(r:3)(u:6)
    float v = 0.f;
    #pragma unroll
    for (int p = 0; p < 8; ++p) v += red[p * 1024 + oi];
    int c  = oi & 63;
    int r  = (oi >> 6) & 7;
    int so = oi >> 9;
    float* dst = so ? ko : qo;
    dst[(size_t)(row0 + r) * UU + c] = v;
  }
}

// ---------------------------------------------------------------------------
// band phase: 8 query rows, NJ<=71 key rows. smem: qpb [0,512), ks [512,5120),
// at [5120,5696).
// ---------------------------------------------------------------------------
__device__ __forceinline__ void band_phase(
    float* __restrict__ smem, int tile,
    const float* __restrict__ x,  const float* __restrict__ qi,
    const float* __restrict__ ki, const float* __restrict__ bh,
    const float* __restrict__ Wa, const float* __restrict__ ba,
    float* __restrict__ out)
{
  float* qpb = smem;            // 8*64
  float* ks  = smem + 512;      // 72*64
  float* at  = smem + 5120;     // 72*8

  const int tid = threadIdx.x;
  const int b   = tile >> 7;
  const int i0  = (tile & 127) * 8;

  const int jlo = max(0, i0 - HW);
  const int jhi = min(TT, i0 + 8 - 1 + HW);      // exclusive
  const int NJ  = jhi - jlo;                     // 39..71

  // ---- stage q(+bh), k ----
  {
    if (tid < 128) {
      float4 qv = ((const float4*)(qi + (size_t)(b * TT + i0) * UU))[tid];
      float4 bv = ((const float4*)bh)[tid & 15];
      qv.x += bv.x; qv.y += bv.y; qv.z += bv.z; qv.w += bv.w;
      ((float4*)qpb)[tid] = qv;
    }
    const float4* ksrc = (const float4*)(ki + (size_t)(b * TT + jlo) * UU);
    float4* kdst = (float4*)ks;
    const int nk4 = NJ * (UU / 4);
    for (int i2 = tid; i2 < nk4; i2 += 512) kdst[i2] = ksrc[i2];
  }
  __syncthreads();

  const float bav = ba[0];

  // ---- stage 1: scores e[i][j] ----
  {
    const int w    = tid >> 6;          // wave id: j-stride 8
    const int lane = tid & 63;
    const int g    = lane >> 3;         // i = i0 + g
    const int uc   = (lane & 7) * 8;    // 8-u chunk per lane
    float qv[8], wv[8];
    #pragma unroll
    for (int s = 0; s < 8; ++s) qv[s] = qpb[g * UU + uc + s];
    {
      float4 wa0 = *(const float4*)(Wa + uc);
      float4 wa1 = *(const float4*)(Wa + uc + 4);
      wv[0] = wa0.x; wv[1] = wa0.y; wv[2] = wa0.z; wv[3] = wa0.w;
      wv[4] = wa1.x; wv[5] = wa1.y; wv[6] = wa1.z; wv[7] = wa1.w;
    }
    const int ig = i0 + g;
    for (int j = w; j < NJ; j += 8) {
      const float* kp = ks + j * UU + uc;
      float s0 = 0.f;
      #pragma unroll
      for (int s = 0; s < 8; ++s) {
        float z = qv[s] + kp[s];
        s0 += tanh_fast(z) * wv[s];
      }
      s0 += __shfl_xor(s0, 1);
      s0 += __shfl_xor(s0, 2);
      s0 += __shfl_xor(s0, 4);
      const int jg = jlo + j;
      const bool inband = (jg >= ig - HW) && (jg < ig + HW);
      if ((lane & 7) == 0) at[j * 8 + g] = inband ? (s0 + bav) : -1e30f;
    }
  }
  __syncthreads();

  // ---- stage 2: softmax per row over j (one wave per row) ----
  {
    const int row = tid >> 6;   // 0..7
    const int l   = tid & 63;
    float v0 = (l      < NJ) ? at[(l     ) * 8 + row] : -1e30f;
    float v1 = (l + 64 < NJ) ? at[(l + 64) * 8 + row] : -1e30f;
    float m = fmaxf(v0, v1);
    #pragma unroll
    for (int off = 32; off >= 1; off >>= 1) m = fmaxf(m, __shfl_xor(m, off));
    float e0 = __expf(v0 - m);
    float e1 = __expf(v1 - m);
    float ssum = e0 + e1;
    #pragma unroll
    for (int off = 32; off >= 1; off >>= 1) ssum += __shfl_xor(ssum, off);
    float inv = 1.0f / ssum;
    if (l      < NJ) at[(l     ) * 8 + row] = e0 * inv;
    if (l + 64 < NJ) at[(l + 64) * 8 + row] = e1 * inv;
  }
  __syncthreads();

  // ---- stage 3: v = a @ x  (thread owns float2 d-slice, all 8 rows) ----
  {
    float2 vacc[8];
    #pragma unroll
    for (int i = 0; i < 8; ++i) vacc[i] = make_float2(0.f, 0.f);
    const float* xb = x + (size_t)(b * TT + jlo) * DD + 2 * tid;

    float2 xn  = *(const float2*)(xb);
    float4 an0 = *(const float4*)(at);
    float4 an1 = *(const float4*)(at + 4);

    for (int j = 0; j < NJ; ++j) {
      float2 xv = xn;
      float4 a0 = an0, a1 = an1;
      if (j + 1 < NJ) {
        xn  = *(const float2*)(xb + (size_t)(j + 1) * DD);
        an0 = *(const float4*)(at + (j + 1) * 8);
        an1 = *(const float4*)(at + (j + 1) * 8 + 4);
      }
      float av[8] = {a0.x, a0.y, a0.z, a0.w, a1.x, a1.y, a1.z, a1.w};
      #pragma unroll
      for (int i = 0; i < 8; ++i) {
        vacc[i].x = __builtin_fmaf(av[i], xv.x, vacc[i].x);
        vacc[i].y = __builtin_fmaf(av[i], xv.y, vacc[i].y);
      }
    }
    float* ob = out + (size_t)(b * TT + i0) * DD + 2 * tid;
    #pragma unroll
    for (int i = 0; i < 8; ++i) *(float2*)(ob + (size_t)i * DD) = vacc[i];
  }
}

// ---------------------------------------------------------------------------
// Fused cooperative kernel: proj phase -> grid sync -> band phase.
// 512 blocks x 512 thr, 64 KB LDS, VGPR<=128 -> 2 blocks/CU co-resident = 512.
// ---------------------------------------------------------------------------
__global__ __launch_bounds__(512, 4) void fused_kernel(
    const float* __restrict__ x,  const float* __restrict__ Wt,
    const float* __restrict__ Wx, const float* __restrict__ bh,
    const float* __restrict__ Wa, const float* __restrict__ ba,
    float* __restrict__ out, float* __restrict__ q, float* __restrict__ k)
{
  __shared__ __align__(16) float smem[16384];    // 64 KB
  const int bid  = blockIdx.x;
  const int tile = (bid & 7) * 64 + (bid >> 3);  // XCD-locality swizzle
  proj_phase(smem, tile, x, Wt, Wx, q, k);
  cg::this_grid().sync();
  band_phase(smem, tile, x, q, k, bh, Wa, ba, out);
}

// ---- fallback (non-cooperative) path: proven R2 two-kernel structure ----
__global__ __launch_bounds__(512) void proj_kernel(
    const float* __restrict__ x, const float* __restrict__ Wt,
    const float* __restrict__ Wx, float* __restrict__ q, float* __restrict__ k)
{
  __shared__ __align__(16) float smem[16384];
  proj_phase(smem, blockIdx.x, x, Wt, Wx, q, k);
}

__global__ __launch_bounds__(512) void band_kernel(
    const float* __restrict__ x,  const float* __restrict__ qi,
    const float* __restrict__ ki, const float* __restrict__ bh,
    const float* __restrict__ Wa, const float* __restrict__ ba,
    float* __restrict__ out)
{
  __shared__ __align__(16) float smem[5696];     // 22.25 KB
  const int bid  = blockIdx.x;
  const int tile = (bid & 7) * 64 + (bid >> 3);
  band_phase(smem, tile, x, qi, ki, bh, Wa, ba, out);
}

// ---------------------------------------------------------------------------
extern "C" void kernel_launch(void* const* d_in, const int* in_sizes, int n_in,
                              void* d_out, int out_size, void* d_ws, size_t ws_size,
                              hipStream_t stream) {
  const float* x  = (const float*)d_in[0];
  const float* Wt = (const float*)d_in[1];
  const float* Wx = (const float*)d_in[2];
  const float* bh = (const float*)d_in[3];
  const float* Wa = (const float*)d_in[4];
  const float* ba = (const float*)d_in[5];
  float* out = (float*)d_out;

  float* q = (float*)d_ws;                       // [4096, 64]
  float* k = q + (size_t)BB * TT * UU;           // [4096, 64]  (2 MB total)

  void* args[] = {(void*)&x, (void*)&Wt, (void*)&Wx, (void*)&bh, (void*)&Wa,
                  (void*)&ba, (void*)&out, (void*)&q, (void*)&k};
  hipError_t err = hipLaunchCooperativeKernel((const void*)fused_kernel,
                                              dim3((BB * TT) / 8), dim3(512),
                                              args, 0, stream);
  if (err != hipSuccess) {
    // non-cooperative fallback: same math, two dispatches
    proj_kernel<<<dim3((BB * TT) / 8), dim3(512), 0, stream>>>(x, Wt, Wx, q, k);
    band_kernel<<<dim3((BB * TT) / 8), dim3(512), 0, stream>>>(x, q, k, bh, Wa, ba, out);
  }
}

// Round 5
// 130.618 us; speedup vs baseline: 1.4922x; 1.4922x over previous
//
#include <hip/hip_runtime.h>

#define BB 4
#define TT 1024
#define DD 1024
#define UU 64
#define HW 32   // WIDTH/2

// tanh via hw exp: tanh(|x|) = (1 - e^{-2|x|}) / (1 + e^{-2|x|}), no overflow, ~1e-6 abs err
__device__ __forceinline__ float tanh_fast(float x) {
  float ax = __builtin_fabsf(x);
  float t = __expf(-2.0f * ax);                     // (0, 1]
  float r = (1.0f - t) * __builtin_amdgcn_rcpf(1.0f + t);
  return __builtin_copysignf(r, x);
}

// ---------------------------------------------------------------------------
// proj: q[row][u] = sum_d x[row][d]*Wt[d][u]; k likewise with Wx.
// grid 512 x 512 threads. Block = 8 rows. Thread = u-pair(32) x sel(2) x kq(8).
// LDS: ONE 32 KB buffer — x-tile during the FMA loop, then (after barrier)
// reused as the 8x1024 partial-sum array. 32 KB + 512 thr + <=64 VGPR ->
// 4 blocks/CU = 32 waves/CU (vs 2 blocks in R2): doubles latency hiding for
// the L2-latency-exposed W loads. W read once per block (268 MB L2 aggregate).
// ---------------------------------------------------------------------------
__global__ __launch_bounds__(512) void proj_kernel(
    const float* __restrict__ x, const float* __restrict__ Wt,
    const float* __restrict__ Wx, float* __restrict__ qo, float* __restrict__ ko)
{
  __shared__ __align__(16) float smem[8 * DD];   // 32 KB (x-tile, then partials)

  const int tid  = threadIdx.x;
  const int row0 = blockIdx.x * 8;

  {
    const float4* src = (const float4*)(x + (size_t)row0 * DD);
    float4* dst = (float4*)smem;
    #pragma unroll
    for (int i = 0; i < 4; ++i) dst[tid + 512 * i] = src[tid + 512 * i];
  }
  __syncthreads();

  const int u2  = tid & 31;          // u pair {2*u2, 2*u2+1}
  const int sel = (tid >> 5) & 1;    // 0 -> Wt/q, 1 -> Wx/k
  const int kq  = tid >> 6;          // d-eighth 0..7 (128 d each)
  const float* __restrict__ Wp = (sel ? Wx : Wt) + 2 * u2;

  float acc0[8], acc1[8];
  #pragma unroll
  for (int r = 0; r < 8; ++r) { acc0[r] = 0.f; acc1[r] = 0.f; }

  const int dbeg = kq * 128;
  #pragma unroll 4
  for (int dc = dbeg; dc < dbeg + 128; dc += 4) {
    float2 w0 = *(const float2*)(Wp + (size_t)(dc + 0) * UU);
    float2 w1 = *(const float2*)(Wp + (size_t)(dc + 1) * UU);
    float2 w2 = *(const float2*)(Wp + (size_t)(dc + 2) * UU);
    float2 w3 = *(const float2*)(Wp + (size_t)(dc + 3) * UU);
    #pragma unroll
    for (int r = 0; r < 8; ++r) {
      float4 xv = *(const float4*)(smem + r * DD + dc);   // wave-uniform broadcast
      acc0[r] = __builtin_fmaf(xv.x, w0.x, __builtin_fmaf(xv.y, w1.x,
                __builtin_fmaf(xv.z, w2.x, __builtin_fmaf(xv.w, w3.x, acc0[r]))));
      acc1[r] = __builtin_fmaf(xv.x, w0.y, __builtin_fmaf(xv.y, w1.y,
                __builtin_fmaf(xv.z, w2.y, __builtin_fmaf(xv.w, w3.y, acc1[r]))));
    }
  }
  __syncthreads();   // x-tile dead; reuse smem as partials

  #pragma unroll
  for (int r = 0; r < 8; ++r) {
    *(float2*)(smem + kq * 1024 + (sel * 8 + r) * 64 + 2 * u2) =
        make_float2(acc0[r], acc1[r]);
  }
  __syncthreads();

  #pragma unroll
  for (int m = 0; m < 2; ++m) {
    int oi = tid + 512 * m;            // (sel:1)(r:3)(u:6)
    float v = 0.f;
    #pragma unroll
    for (int p = 0; p < 8; ++p) v += smem[p * 1024 + oi];
    int c  = oi & 63;
    int r  = (oi >> 6) & 7;
    int so = oi >> 9;
    float* dst = so ? ko : qo;
    dst[(size_t)(row0 + r) * UU + c] = v;
  }
}

// ---------------------------------------------------------------------------
// band: per block, 8 query rows (i0..i0+7) of batch b; NJ<=71 key rows.
// 512 threads (8 waves): scores (8-lane u-chunks, j-stride 8), softmax
// (one wave per row), then per-thread float2 d-slice over all 8 rows with
// software-pipelined x/a loads. 22.25 KB LDS, <=64 VGPR -> 4 blocks/CU.
// ---------------------------------------------------------------------------
__global__ __launch_bounds__(512) void band_kernel(
    const float* __restrict__ x,  const float* __restrict__ qi,
    const float* __restrict__ ki, const float* __restrict__ bh,
    const float* __restrict__ Wa, const float* __restrict__ ba,
    float* __restrict__ out)
{
  __shared__ __align__(16) float qpb[8 * UU];    // q + bh
  __shared__ __align__(16) float ks[72 * UU];    // 18 KB
  __shared__ __align__(16) float at[72 * 8];     // scores / weights, [j][i]

  const int tid  = threadIdx.x;
  const int bid  = blockIdx.x;
  const int tile = (bid & 7) * 64 + (bid >> 3);  // XCD-locality swizzle (512 = 8*64)
  const int b    = tile >> 7;
  const int i0   = (tile & 127) * 8;

  const int jlo = max(0, i0 - HW);
  const int jhi = min(TT, i0 + 8 - 1 + HW);      // exclusive
  const int NJ  = jhi - jlo;                     // 39..71

  // ---- stage q(+bh), k ----
  {
    if (tid < 128) {
      float4 qv = ((const float4*)(qi + (size_t)(b * TT + i0) * UU))[tid];
      float4 bv = ((const float4*)bh)[tid & 15];
      qv.x += bv.x; qv.y += bv.y; qv.z += bv.z; qv.w += bv.w;
      ((float4*)qpb)[tid] = qv;
    }
    const float4* ksrc = (const float4*)(ki + (size_t)(b * TT + jlo) * UU);
    float4* kdst = (float4*)ks;
    const int nk4 = NJ * (UU / 4);
    for (int i2 = tid; i2 < nk4; i2 += 512) kdst[i2] = ksrc[i2];
  }
  __syncthreads();

  const float bav = ba[0];

  // ---- stage 1: scores e[i][j] ----
  {
    const int w    = tid >> 6;          // wave id: j-stride 8
    const int lane = tid & 63;
    const int g    = lane >> 3;         // i = i0 + g
    const int uc   = (lane & 7) * 8;    // 8-u chunk per lane
    float qv[8], wv[8];
    #pragma unroll
    for (int s = 0; s < 8; ++s) qv[s] = qpb[g * UU + uc + s];
    {
      float4 wa0 = *(const float4*)(Wa + uc);
      float4 wa1 = *(const float4*)(Wa + uc + 4);
      wv[0] = wa0.x; wv[1] = wa0.y; wv[2] = wa0.z; wv[3] = wa0.w;
      wv[4] = wa1.x; wv[5] = wa1.y; wv[6] = wa1.z; wv[7] = wa1.w;
    }
    const int ig = i0 + g;
    for (int j = w; j < NJ; j += 8) {
      const float* kp = ks + j * UU + uc;
      float s0 = 0.f;
      #pragma unroll
      for (int s = 0; s < 8; ++s) {
        float z = qv[s] + kp[s];
        s0 += tanh_fast(z) * wv[s];
      }
      s0 += __shfl_xor(s0, 1);
      s0 += __shfl_xor(s0, 2);
      s0 += __shfl_xor(s0, 4);
      const int jg = jlo + j;
      const bool inband = (jg >= ig - HW) && (jg < ig + HW);
      if ((lane & 7) == 0) at[j * 8 + g] = inband ? (s0 + bav) : -1e30f;
    }
  }
  __syncthreads();

  // ---- stage 2: softmax per row over j (one wave per row) ----
  {
    const int row = tid >> 6;   // 0..7
    const int l   = tid & 63;
    float v0 = (l      < NJ) ? at[(l     ) * 8 + row] : -1e30f;
    float v1 = (l + 64 < NJ) ? at[(l + 64) * 8 + row] : -1e30f;
    float m = fmaxf(v0, v1);
    #pragma unroll
    for (int off = 32; off >= 1; off >>= 1) m = fmaxf(m, __shfl_xor(m, off));
    float e0 = __expf(v0 - m);
    float e1 = __expf(v1 - m);
    float ssum = e0 + e1;
    #pragma unroll
    for (int off = 32; off >= 1; off >>= 1) ssum += __shfl_xor(ssum, off);
    float inv = 1.0f / ssum;
    if (l      < NJ) at[(l     ) * 8 + row] = e0 * inv;
    if (l + 64 < NJ) at[(l + 64) * 8 + row] = e1 * inv;
  }
  __syncthreads();

  // ---- stage 3: v = a @ x  (thread owns float2 d-slice, all 8 rows) ----
  {
    float2 vacc[8];
    #pragma unroll
    for (int i = 0; i < 8; ++i) vacc[i] = make_float2(0.f, 0.f);
    const float* xb = x + (size_t)(b * TT + jlo) * DD + 2 * tid;

    float2 xn  = *(const float2*)(xb);
    float4 an0 = *(const float4*)(at);
    float4 an1 = *(const float4*)(at + 4);

    for (int j = 0; j < NJ; ++j) {
      float2 xv = xn;
      float4 a0 = an0, a1 = an1;
      if (j + 1 < NJ) {
        xn  = *(const float2*)(xb + (size_t)(j + 1) * DD);
        an0 = *(const float4*)(at + (j + 1) * 8);
        an1 = *(const float4*)(at + (j + 1) * 8 + 4);
      }
      float av[8] = {a0.x, a0.y, a0.z, a0.w, a1.x, a1.y, a1.z, a1.w};
      #pragma unroll
      for (int i = 0; i < 8; ++i) {
        vacc[i].x = __builtin_fmaf(av[i], xv.x, vacc[i].x);
        vacc[i].y = __builtin_fmaf(av[i], xv.y, vacc[i].y);
      }
    }
    float* ob = out + (size_t)(b * TT + i0) * DD + 2 * tid;
    #pragma unroll
    for (int i = 0; i < 8; ++i) *(float2*)(ob + (size_t)i * DD) = vacc[i];
  }
}

// ---------------------------------------------------------------------------
extern "C" void kernel_launch(void* const* d_in, const int* in_sizes, int n_in,
                              void* d_out, int out_size, void* d_ws, size_t ws_size,
                              hipStream_t stream) {
  const float* x  = (const float*)d_in[0];
  const float* Wt = (const float*)d_in[1];
  const float* Wx = (const float*)d_in[2];
  const float* bh = (const float*)d_in[3];
  const float* Wa = (const float*)d_in[4];
  const float* ba = (const float*)d_in[5];
  float* out = (float*)d_out;

  float* q = (float*)d_ws;                       // [4096, 64]
  float* k = q + (size_t)BB * TT * UU;           // [4096, 64]  (2 MB total)

  proj_kernel<<<dim3((BB * TT) / 8), dim3(512), 0, stream>>>(x, Wt, Wx, q, k);
  band_kernel<<<dim3((BB * TT) / 8), dim3(512), 0, stream>>>(x, q, k, bh, Wa, ba, out);
}

// Round 6
// 118.772 us; speedup vs baseline: 1.6411x; 1.0997x over previous
//
#include <hip/hip_runtime.h>

#define BB 4
#define TT 1024
#define DD 1024
#define UU 64
#define HW 32   // WIDTH/2

// tanh via hw exp: tanh(|x|) = (1 - e^{-2|x|}) / (1 + e^{-2|x|}), no overflow, ~1e-6 abs err
__device__ __forceinline__ float tanh_fast(float x) {
  float ax = __builtin_fabsf(x);
  float t = __expf(-2.0f * ax);                     // (0, 1]
  float r = (1.0f - t) * __builtin_amdgcn_rcpf(1.0f + t);
  return __builtin_copysignf(r, x);
}

// ---------------------------------------------------------------------------
// proj: q[row][u] = sum_d x[row][d]*Wt[d][u]; k likewise with Wx.
// grid 512 x 512 threads. Block = 8 rows. Thread = u-pair(32) x sel(2) x kq(8).
// LDS: ONE 32 KB buffer — x-tile during the FMA loop, then (after barrier)
// reused as the 8x1024 partial-sum array. 4 blocks/CU = 32 waves/CU.
// ---------------------------------------------------------------------------
__global__ __launch_bounds__(512) void proj_kernel(
    const float* __restrict__ x, const float* __restrict__ Wt,
    const float* __restrict__ Wx, float* __restrict__ qo, float* __restrict__ ko)
{
  __shared__ __align__(16) float smem[8 * DD];   // 32 KB (x-tile, then partials)

  const int tid  = threadIdx.x;
  const int row0 = blockIdx.x * 8;

  {
    const float4* src = (const float4*)(x + (size_t)row0 * DD);
    float4* dst = (float4*)smem;
    #pragma unroll
    for (int i = 0; i < 4; ++i) dst[tid + 512 * i] = src[tid + 512 * i];
  }
  __syncthreads();

  const int u2  = tid & 31;          // u pair {2*u2, 2*u2+1}
  const int sel = (tid >> 5) & 1;    // 0 -> Wt/q, 1 -> Wx/k
  const int kq  = tid >> 6;          // d-eighth 0..7 (128 d each)
  const float* __restrict__ Wp = (sel ? Wx : Wt) + 2 * u2;

  float acc0[8], acc1[8];
  #pragma unroll
  for (int r = 0; r < 8; ++r) { acc0[r] = 0.f; acc1[r] = 0.f; }

  const int dbeg = kq * 128;
  #pragma unroll 4
  for (int dc = dbeg; dc < dbeg + 128; dc += 4) {
    float2 w0 = *(const float2*)(Wp + (size_t)(dc + 0) * UU);
    float2 w1 = *(const float2*)(Wp + (size_t)(dc + 1) * UU);
    float2 w2 = *(const float2*)(Wp + (size_t)(dc + 2) * UU);
    float2 w3 = *(const float2*)(Wp + (size_t)(dc + 3) * UU);
    #pragma unroll
    for (int r = 0; r < 8; ++r) {
      float4 xv = *(const float4*)(smem + r * DD + dc);   // wave-uniform broadcast
      acc0[r] = __builtin_fmaf(xv.x, w0.x, __builtin_fmaf(xv.y, w1.x,
                __builtin_fmaf(xv.z, w2.x, __builtin_fmaf(xv.w, w3.x, acc0[r]))));
      acc1[r] = __builtin_fmaf(xv.x, w0.y, __builtin_fmaf(xv.y, w1.y,
                __builtin_fmaf(xv.z, w2.y, __builtin_fmaf(xv.w, w3.y, acc1[r]))));
    }
  }
  __syncthreads();   // x-tile dead; reuse smem as partials

  #pragma unroll
  for (int r = 0; r < 8; ++r) {
    *(float2*)(smem + kq * 1024 + (sel * 8 + r) * 64 + 2 * u2) =
        make_float2(acc0[r], acc1[r]);
  }
  __syncthreads();

  #pragma unroll
  for (int m = 0; m < 2; ++m) {
    int oi = tid + 512 * m;            // (sel:1)(r:3)(u:6)
    float v = 0.f;
    #pragma unroll
    for (int p = 0; p < 8; ++p) v += smem[p * 1024 + oi];
    int c  = oi & 63;
    int r  = (oi >> 6) & 7;
    int so = oi >> 9;
    float* dst = so ? ko : qo;
    dst[(size_t)(row0 + r) * UU + c] = v;
  }
}

// ---------------------------------------------------------------------------
// band: per block, 8 query rows (i0..i0+7) of batch b; NJ<=71 key rows.
// 512 threads (8 waves): scores (8-lane u-chunks, j-stride 8), softmax
// (one wave per row), then per-thread float2 d-slice over all 8 rows.
// Stage-3 j-loop is the PLAIN R2 form: direct loads + unroll 2 — the
// compiler keeps multiple loads in flight; explicit depth-1 pipelining
// regressed (R3/R5, m141-style scheduler defeat).
// ---------------------------------------------------------------------------
__global__ __launch_bounds__(512) void band_kernel(
    const float* __restrict__ x,  const float* __restrict__ qi,
    const float* __restrict__ ki, const float* __restrict__ bh,
    const float* __restrict__ Wa, const float* __restrict__ ba,
    float* __restrict__ out)
{
  __shared__ __align__(16) float qpb[8 * UU];    // q + bh
  __shared__ __align__(16) float ks[72 * UU];    // 18 KB
  __shared__ __align__(16) float at[72 * 8];     // scores / weights, [j][i]

  const int tid  = threadIdx.x;
  const int bid  = blockIdx.x;
  const int tile = (bid & 7) * 64 + (bid >> 3);  // XCD-locality swizzle (512 = 8*64)
  const int b    = tile >> 7;
  const int i0   = (tile & 127) * 8;

  const int jlo = max(0, i0 - HW);
  const int jhi = min(TT, i0 + 8 - 1 + HW);      // exclusive
  const int NJ  = jhi - jlo;                     // 39..71

  // ---- stage q(+bh), k ----
  {
    if (tid < 128) {
      float4 qv = ((const float4*)(qi + (size_t)(b * TT + i0) * UU))[tid];
      float4 bv = ((const float4*)bh)[tid & 15];
      qv.x += bv.x; qv.y += bv.y; qv.z += bv.z; qv.w += bv.w;
      ((float4*)qpb)[tid] = qv;
    }
    const float4* ksrc = (const float4*)(ki + (size_t)(b * TT + jlo) * UU);
    float4* kdst = (float4*)ks;
    const int nk4 = NJ * (UU / 4);
    for (int i2 = tid; i2 < nk4; i2 += 512) kdst[i2] = ksrc[i2];
  }
  __syncthreads();

  const float bav = ba[0];

  // ---- stage 1: scores e[i][j] ----
  {
    const int w    = tid >> 6;          // wave id: j-stride 8
    const int lane = tid & 63;
    const int g    = lane >> 3;         // i = i0 + g
    const int uc   = (lane & 7) * 8;    // 8-u chunk per lane
    float qv[8], wv[8];
    #pragma unroll
    for (int s = 0; s < 8; ++s) qv[s] = qpb[g * UU + uc + s];
    {
      float4 wa0 = *(const float4*)(Wa + uc);
      float4 wa1 = *(const float4*)(Wa + uc + 4);
      wv[0] = wa0.x; wv[1] = wa0.y; wv[2] = wa0.z; wv[3] = wa0.w;
      wv[4] = wa1.x; wv[5] = wa1.y; wv[6] = wa1.z; wv[7] = wa1.w;
    }
    const int ig = i0 + g;
    for (int j = w; j < NJ; j += 8) {
      const float* kp = ks + j * UU + uc;
      float s0 = 0.f;
      #pragma unroll
      for (int s = 0; s < 8; ++s) {
        float z = qv[s] + kp[s];
        s0 += tanh_fast(z) * wv[s];
      }
      s0 += __shfl_xor(s0, 1);
      s0 += __shfl_xor(s0, 2);
      s0 += __shfl_xor(s0, 4);
      const int jg = jlo + j;
      const bool inband = (jg >= ig - HW) && (jg < ig + HW);
      if ((lane & 7) == 0) at[j * 8 + g] = inband ? (s0 + bav) : -1e30f;
    }
  }
  __syncthreads();

  // ---- stage 2: softmax per row over j (one wave per row) ----
  {
    const int row = tid >> 6;   // 0..7
    const int l   = tid & 63;
    float v0 = (l      < NJ) ? at[(l     ) * 8 + row] : -1e30f;
    float v1 = (l + 64 < NJ) ? at[(l + 64) * 8 + row] : -1e30f;
    float m = fmaxf(v0, v1);
    #pragma unroll
    for (int off = 32; off >= 1; off >>= 1) m = fmaxf(m, __shfl_xor(m, off));
    float e0 = __expf(v0 - m);
    float e1 = __expf(v1 - m);
    float ssum = e0 + e1;
    #pragma unroll
    for (int off = 32; off >= 1; off >>= 1) ssum += __shfl_xor(ssum, off);
    float inv = 1.0f / ssum;
    if (l      < NJ) at[(l     ) * 8 + row] = e0 * inv;
    if (l + 64 < NJ) at[(l + 64) * 8 + row] = e1 * inv;
  }
  __syncthreads();

  // ---- stage 3: v = a @ x  (thread owns float2 d-slice, all 8 rows) ----
  {
    float2 vacc[8];
    #pragma unroll
    for (int i = 0; i < 8; ++i) vacc[i] = make_float2(0.f, 0.f);
    const float* xb = x + (size_t)(b * TT + jlo) * DD + 2 * tid;
    #pragma unroll 2
    for (int j = 0; j < NJ; ++j) {
      float2 xv = *(const float2*)(xb + (size_t)j * DD);
      float4 a0 = *(const float4*)(at + j * 8);
      float4 a1 = *(const float4*)(at + j * 8 + 4);
      float av[8] = {a0.x, a0.y, a0.z, a0.w, a1.x, a1.y, a1.z, a1.w};
      #pragma unroll
      for (int i = 0; i < 8; ++i) {
        vacc[i].x = __builtin_fmaf(av[i], xv.x, vacc[i].x);
        vacc[i].y = __builtin_fmaf(av[i], xv.y, vacc[i].y);
      }
    }
    float* ob = out + (size_t)(b * TT + i0) * DD + 2 * tid;
    #pragma unroll
    for (int i = 0; i < 8; ++i) *(float2*)(ob + (size_t)i * DD) = vacc[i];
  }
}

// ---------------------------------------------------------------------------
extern "C" void kernel_launch(void* const* d_in, const int* in_sizes, int n_in,
                              void* d_out, int out_size, void* d_ws, size_t ws_size,
                              hipStream_t stream) {
  const float* x  = (const float*)d_in[0];
  const float* Wt = (const float*)d_in[1];
  const float* Wx = (const float*)d_in[2];
  const float* bh = (const float*)d_in[3];
  const float* Wa = (const float*)d_in[4];
  const float* ba = (const float*)d_in[5];
  float* out = (float*)d_out;

  float* q = (float*)d_ws;                       // [4096, 64]
  float* k = q + (size_t)BB * TT * UU;           // [4096, 64]  (2 MB total)

  proj_kernel<<<dim3((BB * TT) / 8), dim3(512), 0, stream>>>(x, Wt, Wx, q, k);
  band_kernel<<<dim3((BB * TT) / 8), dim3(512), 0, stream>>>(x, q, k, bh, Wa, ba, out);
}